// Round 2
// baseline (1255.644 us; speedup 1.0000x reference)
//
#include <hip/hip_runtime.h>
#include <hip/hip_fp16.h>
#include <hip/hip_cooperative_groups.h>

namespace cg = cooperative_groups;

#define NN 512
#define RPT 16     // rows per thread
#define WAVES 16   // waves per block (1024 threads)

union H2U { uint32_t u; __half2 h; };

__device__ __forceinline__ float wave_reduce_sum(float v) {
    #pragma unroll
    for (int off = 32; off > 0; off >>= 1)
        v += __shfl_xor(v, off, 64);
    return v;
}

__device__ __forceinline__ void unpack8(const uint32_t q[4], float e[8]) {
    #pragma unroll
    for (int k = 0; k < 4; ++k) {
        H2U u; u.u = q[k];
        float2 f = __half22float2(u.h);
        e[2 * k]     = f.x;
        e[2 * k + 1] = f.y;
    }
}

// 2 blocks per matrix; each block keeps its 256x512 half of E = exp(S) in
// registers (fp16 packed, 64 VGPRs/thread). Row normalizations are
// block-local; column normalizations exchange one 512-float partial-sum
// vector between the pair via global memory + grid.sync().
__global__ __launch_bounds__(1024, 4)
void sinkhorn_coop(const float* __restrict__ Sg,
                   float* __restrict__ xchg,
                   float* __restrict__ outg) {
    cg::grid_group grid = cg::this_grid();

    const int blk  = blockIdx.x;
    const int mat  = blk >> 1;
    const int half = blk & 1;
    const size_t base = (size_t)mat * NN * NN + (size_t)half * (NN / 2) * NN;
    const float* S = Sg + base;
    float* out = outg + base;

    __shared__ float Av[NN / 2];          // 1/row-sums for this block's 256 rows
    __shared__ float Bv[NN];              // 1/col-sums (full 512)
    __shared__ float part[WAVES][NN];     // per-wave column partials (32 KB)

    const int tid  = threadIdx.x;
    const int lane = tid & 63;
    const int w    = tid >> 6;

    // E fragment: local rows w*16+rr (rr<16), cols lane*8..lane*8+7
    uint32_t Ereg[RPT][4];

    // ---- pass 0: E = exp(S); row sums with B = 1 -> Av ----
    #pragma unroll
    for (int rr = 0; rr < RPT; ++rr) {
        const int lr = w * RPT + rr;
        const float4* p = reinterpret_cast<const float4*>(S + lr * NN + lane * 8);
        float4 x0 = p[0];
        float4 x1 = p[1];
        float e[8];
        e[0] = __expf(x0.x); e[1] = __expf(x0.y);
        e[2] = __expf(x0.z); e[3] = __expf(x0.w);
        e[4] = __expf(x1.x); e[5] = __expf(x1.y);
        e[6] = __expf(x1.z); e[7] = __expf(x1.w);
        #pragma unroll
        for (int q = 0; q < 4; ++q) {
            H2U u;
            u.h = __floats2half2_rn(e[2 * q], e[2 * q + 1]);
            Ereg[rr][q] = u.u;
        }
        float acc = ((e[0] + e[1]) + (e[2] + e[3])) + ((e[4] + e[5]) + (e[6] + e[7]));
        acc = wave_reduce_sum(acc);
        if (lane == 0) Av[lr] = 1.0f / acc;
    }
    __syncthreads();

    for (int it = 0; it < 10; ++it) {
        // ---- col pass: B_j = 1 / sum_i E_ij * A_i (cross-block) ----
        float c[8] = {0.f, 0.f, 0.f, 0.f, 0.f, 0.f, 0.f, 0.f};
        #pragma unroll
        for (int rr = 0; rr < RPT; ++rr) {
            const float a = Av[w * RPT + rr];   // wave-uniform broadcast
            float e[8];
            unpack8(Ereg[rr], e);
            #pragma unroll
            for (int k = 0; k < 8; ++k) c[k] += e[k] * a;
        }
        *reinterpret_cast<float4*>(&part[w][lane * 8])     = make_float4(c[0], c[1], c[2], c[3]);
        *reinterpret_cast<float4*>(&part[w][lane * 8 + 4]) = make_float4(c[4], c[5], c[6], c[7]);
        __syncthreads();

        float mine = 0.f;
        if (tid < NN) {
            #pragma unroll
            for (int k = 0; k < WAVES; ++k) mine += part[k][tid];
            xchg[(((size_t)mat * 2 + half) * 2 + (it & 1)) * NN + tid] = mine;
        }
        __threadfence();
        grid.sync();
        if (tid < NN) {
            float theirs = xchg[(((size_t)mat * 2 + (1 - half)) * 2 + (it & 1)) * NN + tid];
            Bv[tid] = 1.0f / (mine + theirs);   // fp add commutative -> both blocks identical
        }
        __syncthreads();

        // ---- row pass: A_i = 1 / sum_j E_ij * B_j (block-local) ----
        if (it < 9) {
            float b[8];
            #pragma unroll
            for (int k = 0; k < 8; ++k) b[k] = Bv[lane * 8 + k];
            #pragma unroll
            for (int rr = 0; rr < RPT; ++rr) {
                float e[8];
                unpack8(Ereg[rr], e);
                float acc = 0.f;
                #pragma unroll
                for (int k = 0; k < 8; ++k) acc += e[k] * b[k];
                acc = wave_reduce_sum(acc);
                if (lane == 0) Av[w * RPT + rr] = 1.0f / acc;
            }
            __syncthreads();
        }
    }

    // ---- final: out_ij = E_ij * A_i * B_j ----
    {
        float b[8];
        #pragma unroll
        for (int k = 0; k < 8; ++k) b[k] = Bv[lane * 8 + k];
        #pragma unroll
        for (int rr = 0; rr < RPT; ++rr) {
            const int lr = w * RPT + rr;
            const float a = Av[lr];
            float e[8];
            unpack8(Ereg[rr], e);
            float* op = out + lr * NN + lane * 8;
            reinterpret_cast<float4*>(op)[0] =
                make_float4(e[0] * a * b[0], e[1] * a * b[1], e[2] * a * b[2], e[3] * a * b[3]);
            reinterpret_cast<float4*>(op)[1] =
                make_float4(e[4] * a * b[4], e[5] * a * b[5], e[6] * a * b[6], e[7] * a * b[7]);
        }
    }
}

extern "C" void kernel_launch(void* const* d_in, const int* in_sizes, int n_in,
                              void* d_out, int out_size, void* d_ws, size_t ws_size,
                              hipStream_t stream) {
    const float* S = reinterpret_cast<const float*>(d_in[0]);
    float* out = reinterpret_cast<float*>(d_out);
    float* xchg = reinterpret_cast<float*>(d_ws);
    const int nmat = in_sizes[0] / (NN * NN);   // 128 for (8,16,512,512)

    dim3 grid(2 * nmat);
    dim3 block(1024);
    void* args[] = { (void*)&S, (void*)&xchg, (void*)&out };
    (void)hipLaunchCooperativeKernel(reinterpret_cast<const void*>(&sinkhorn_coop),
                                     grid, block, args, 0, stream);
}

// Round 3
// 1124.906 us; speedup vs baseline: 1.1162x; 1.1162x over previous
//
#include <hip/hip_runtime.h>
#include <hip/hip_fp16.h>
#include <hip/hip_cooperative_groups.h>

namespace cg = cooperative_groups;

#define NN 512
#define HROWS 256          // rows per block (half matrix)
#define WAVES 8            // 512 threads
#define RPW 32             // rows per wave
#define NITER 10

union H2U { uint32_t u; __half2 h; };

__device__ __forceinline__ float wave_reduce_sum(float v) {
    #pragma unroll
    for (int off = 32; off > 0; off >>= 1)
        v += __shfl_xor(v, off, 64);
    return v;   // all 64 lanes hold the sum
}

__device__ __forceinline__ void unpack8(const uint32_t q[4], float e[8]) {
    #pragma unroll
    for (int k = 0; k < 4; ++k) {
        H2U u; u.u = q[k];
        float2 f = __half22float2(u.h);
        e[2 * k]     = f.x;
        e[2 * k + 1] = f.y;
    }
}

// 2 blocks per matrix (block owns 256 rows, E=exp(S) register-resident as
// packed fp16: 128 VGPRs/thread at 512 thr/block). Fused sweep per Sinkhorn
// iteration: per row compute A_i = 1/dot(E_i, B_prev) (wave butterfly), then
// accumulate col partials c_j += E_ij*A_i. Column sums are completed by a
// pairwise partner exchange through global ws with release/acquire flags.
__global__ __launch_bounds__(512, 2)
void sinkhorn_pair(const float* __restrict__ Sg,
                   float* __restrict__ outg,
                   int* __restrict__ flags,
                   float* __restrict__ xdata,
                   int nmat) {
    cg::grid_group grid = cg::this_grid();

    const int blk  = blockIdx.x;
    const int mat  = blk % nmat;
    const int half = blk / nmat;           // pair partner: (1-half)*nmat+mat (same XCD under %8 dispatch)
    const size_t base = (size_t)mat * NN * NN + (size_t)half * HROWS * NN;
    const float* S = Sg + base;
    float* out = outg + base;

    __shared__ float Bv[NN];               // 1/col-sums (full 512)
    __shared__ float Av[HROWS];            // 1/row-sums (this block's rows)
    __shared__ float part[WAVES][NN];      // per-wave col partials (16 KB)

    const int tid  = threadIdx.x;
    const int lane = tid & 63;
    const int w    = tid >> 6;

    // ---- reset partner flags (ws is NOT re-poisoned between graph replays) ----
    if (tid < NITER)
        flags[(tid * 2 + half) * nmat + mat] = 0;
    __threadfence();
    grid.sync();

    // E fragment: rows w*32+rr (local), cols lane*8..+7, packed half2 x4
    uint32_t Ereg[RPW][4];
    float c[8] = {0.f, 0.f, 0.f, 0.f, 0.f, 0.f, 0.f, 0.f};

    // ---- sweep 0: E = exp(S); A = 1/rowsum (B=1); col partials with A ----
    #pragma unroll
    for (int rr = 0; rr < RPW; ++rr) {
        const int lr = w * RPW + rr;
        const float4* p = reinterpret_cast<const float4*>(S + (size_t)lr * NN + lane * 8);
        float4 x0 = p[0];
        float4 x1 = p[1];
        float e[8];
        e[0] = __expf(x0.x); e[1] = __expf(x0.y);
        e[2] = __expf(x0.z); e[3] = __expf(x0.w);
        e[4] = __expf(x1.x); e[5] = __expf(x1.y);
        e[6] = __expf(x1.z); e[7] = __expf(x1.w);
        #pragma unroll
        for (int q = 0; q < 4; ++q) {
            H2U u;
            u.h = __floats2half2_rn(e[2 * q], e[2 * q + 1]);
            Ereg[rr][q] = u.u;
        }
        float rs = ((e[0] + e[1]) + (e[2] + e[3])) + ((e[4] + e[5]) + (e[6] + e[7]));
        rs = wave_reduce_sum(rs);
        const float a = 1.0f / rs;
        if (lane == 0) Av[lr] = a;
        #pragma unroll
        for (int k = 0; k < 8; ++k) c[k] += e[k] * a;
    }

    // ---- per-iteration: complete col sums via partner exchange -> Bv ----
    for (int t = 0; t < NITER; ++t) {
        // (c[] holds this block's col partials for iteration t)
        *reinterpret_cast<float4*>(&part[w][lane * 8])     = make_float4(c[0], c[1], c[2], c[3]);
        *reinterpret_cast<float4*>(&part[w][lane * 8 + 4]) = make_float4(c[4], c[5], c[6], c[7]);
        __syncthreads();

        float mine = 0.f;
        #pragma unroll
        for (int k = 0; k < WAVES; ++k) mine += part[k][tid];

        const int myslot = (t * 2 + half) * nmat + mat;
        const int pfslot = (t * 2 + (1 - half)) * nmat + mat;
        xdata[(size_t)myslot * NN + tid] = mine;
        __threadfence();
        __syncthreads();
        if (tid == 0)
            __hip_atomic_store(&flags[myslot], 1, __ATOMIC_RELEASE, __HIP_MEMORY_SCOPE_AGENT);
        while (__hip_atomic_load(&flags[pfslot], __ATOMIC_ACQUIRE, __HIP_MEMORY_SCOPE_AGENT) == 0) {}
        const float theirs = xdata[(size_t)pfslot * NN + tid];
        Bv[tid] = 1.0f / (mine + theirs);   // commutative -> identical in both blocks
        __syncthreads();

        if (t == NITER - 1) break;          // B^(9) done; A^(9) already in Av

        // ---- fused sweep t+1: A_i = 1/dot(E_i, B); c_j += E_ij * A_i ----
        float b[8];
        #pragma unroll
        for (int k = 0; k < 8; ++k) b[k] = Bv[lane * 8 + k];
        #pragma unroll
        for (int k = 0; k < 8; ++k) c[k] = 0.f;
        #pragma unroll
        for (int rr = 0; rr < RPW; ++rr) {
            float e[8];
            unpack8(Ereg[rr], e);
            float d = 0.f;
            #pragma unroll
            for (int k = 0; k < 8; ++k) d += e[k] * b[k];
            d = wave_reduce_sum(d);
            const float a = 1.0f / d;
            if (lane == 0) Av[w * RPW + rr] = a;
            #pragma unroll
            for (int k = 0; k < 8; ++k) c[k] += e[k] * a;
        }
        __syncthreads();   // all waves done with part[] reads? (part reused next iter after write)
    }

    // ---- final: out_ij = E_ij * A_i * B_j ----
    {
        float b[8];
        #pragma unroll
        for (int k = 0; k < 8; ++k) b[k] = Bv[lane * 8 + k];
        #pragma unroll
        for (int rr = 0; rr < RPW; ++rr) {
            const int lr = w * RPW + rr;
            const float a = Av[lr];
            float e[8];
            unpack8(Ereg[rr], e);
            float* op = out + (size_t)lr * NN + lane * 8;
            reinterpret_cast<float4*>(op)[0] =
                make_float4(e[0] * a * b[0], e[1] * a * b[1], e[2] * a * b[2], e[3] * a * b[3]);
            reinterpret_cast<float4*>(op)[1] =
                make_float4(e[4] * a * b[4], e[5] * a * b[5], e[6] * a * b[6], e[7] * a * b[7]);
        }
    }
}

extern "C" void kernel_launch(void* const* d_in, const int* in_sizes, int n_in,
                              void* d_out, int out_size, void* d_ws, size_t ws_size,
                              hipStream_t stream) {
    const float* S = reinterpret_cast<const float*>(d_in[0]);
    float* out = reinterpret_cast<float*>(d_out);
    const int nmat = in_sizes[0] / (NN * NN);   // 128 for (8,16,512,512)

    // ws layout: [flags: NITER*2*nmat ints][pad to 64KB][xdata: NITER*2*nmat*NN floats]
    int* flags = reinterpret_cast<int*>(d_ws);
    float* xdata = reinterpret_cast<float*>(reinterpret_cast<char*>(d_ws) + (64 << 10));

    dim3 grid(2 * nmat);
    dim3 block(512);
    void* args[] = { (void*)&S, (void*)&out, (void*)&flags, (void*)&xdata, (void*)&nmat };
    (void)hipLaunchCooperativeKernel(reinterpret_cast<const void*>(&sinkhorn_pair),
                                     grid, block, args, 0, stream);
}